// Round 5
// baseline (320.511 us; speedup 1.0000x reference)
//
#include <hip/hip_runtime.h>
#include <hip/hip_cooperative_groups.h>
#include <stdint.h>

namespace cg = cooperative_groups;

// ---------------------------------------------------------------------------
// Attention: out = softmax(Q K^T) V,  N=8, S=2048, E=512, fp32 in/out.
// R11 = R9's proven structure (attn 118us) fused into ONE cooperative kernel:
//   phase A: Q/K/V -> fp16 frag layout (R9 pre-pass work, 3 jobs/block over
//            512 blocks x 512 thr, LDS overlay), grid.sync(),
//   phase B: R9 attention VERBATIM (K top-of-loop, V prefetch after S).
// R10 post-mortem: K register pipeline regressed (vmcnt wait pinned at the
// kcur=knxt copy after PV + 16 live VGPRs -> occupancy drop); reverted.
// Gap accounting: total-attn = ~25us/512 pre-pass blocks + ~46us launch gap;
// fusion attacks both. Fallback to two-kernel R9 path if cooperative enqueue
// is rejected (e.g. under graph capture restrictions).
// ---------------------------------------------------------------------------

typedef __attribute__((ext_vector_type(8))) _Float16 half8;   // MFMA A/B frag
typedef __attribute__((ext_vector_type(2))) _Float16 half2;
typedef __attribute__((ext_vector_type(4))) float    floatx4; // MFMA C/D frag

#define NBATCH 8
#define SEQ    2048
#define EDIM   512
static constexpr size_t NE = (size_t)NBATCH * SEQ * EDIM;  // 8388608 elems/tensor

// Barrier WITHOUT vmcnt drain: LDS ordering only; global loads in flight stay
// in flight (their consumers get compiler-inserted vmcnt waits).
__device__ __forceinline__ void block_sync_lds() {
  asm volatile("s_waitcnt lgkmcnt(0)\n\ts_barrier" ::: "memory");
}

__device__ __forceinline__ half8 cvt8(float4 a, float4 b) {
  half8 h;
  h[0] = (_Float16)a.x; h[1] = (_Float16)a.y; h[2] = (_Float16)a.z; h[3] = (_Float16)a.w;
  h[4] = (_Float16)b.x; h[5] = (_Float16)b.y; h[6] = (_Float16)b.z; h[7] = (_Float16)b.w;
  return h;
}

// ---------------------------------------------------------------------------
// Fragment layout contract (A/B-frag 16x16x32): lane l holds
//   [dim16 = l&15][k = (l>>4)*8 + j].
//  Q/K: xf[((n*128 + rt)*16 + est)*512 + lane*8 + j]   (rt = row>>4, est = e>>5)
//  V:   vf[((n*64 + kt)*32 + et)*512 + lane*8 + j]     (kt = krow>>5, et = e>>4,
//        dim16 = e-col, k = krow within 32-tile)
// ---------------------------------------------------------------------------

// ===========================================================================
// Fused cooperative kernel: 512 blocks x 512 threads (exactly 2 blocks/CU).
// ===========================================================================
__launch_bounds__(512, 4)
__global__ void attn_all(const float* __restrict__ q, const float* __restrict__ k,
                         const float* __restrict__ v,
                         _Float16* __restrict__ qf, _Float16* __restrict__ kf,
                         _Float16* __restrict__ vf, float* __restrict__ out) {
  // LDS overlay: phase A staging 32x260 f32 = 33280 B; phase B attn = 21376 B.
  __shared__ __align__(16) char smem[33280];

  const int tid = threadIdx.x;

  // ------------------------- phase A: make frags --------------------------
  {
    float (*lds)[260] = reinterpret_cast<float (*)[260]>(smem);
    const int b = blockIdx.x;             // 8 n x 64 kt
    const int n = b >> 6, kt = b & 63;
#pragma unroll 1
    for (int seg = 0; seg < 3; seg++) {   // 0=Q, 1=K, 2=V
      const float* src = (seg == 0 ? q : seg == 1 ? k : v) +
                         ((size_t)n * SEQ + kt * 32) * EDIM;
      if (seg) __syncthreads();           // LDS reuse across jobs
#pragma unroll 1
      for (int eh = 0; eh < 2; eh++) {
        if (eh) __syncthreads();
#pragma unroll
        for (int i = 0; i < 4; i++) {     // stage 32 rows x 256 f32 (coalesced)
          int c = i * 512 + tid;
          int row = c >> 6, col4 = c & 63;
          float4 x = *reinterpret_cast<const float4*>(src + (size_t)row * EDIM + eh * 256 + col4 * 4);
          *reinterpret_cast<float4*>(&lds[row][col4 * 4]) = x;
        }
        __syncthreads();
        if (seg < 2) {
          _Float16* dst = (seg == 0 ? qf : kf) + ((size_t)(n * 128 + kt * 2) * 16) * 512;
#pragma unroll
          for (int i = 0; i < 2; i++) {   // emit 1024 half8 chunks / half
            int fl = i * 512 + tid;
            int lane = fl & 63, idx = fl >> 6;        // idx 0..15
            int est_l = idx & 7, rt_l = idx >> 3;     // est_l 0..7, rt_l 0..1
            int m15 = lane & 15, q4 = lane >> 4;
            const float* p = &lds[rt_l * 16 + m15][est_l * 32 + q4 * 8];
            float4 a = *reinterpret_cast<const float4*>(p);
            float4 bb = *reinterpret_cast<const float4*>(p + 4);
            *reinterpret_cast<half8*>(dst + ((size_t)(rt_l * 16 + eh * 8 + est_l)) * 512 + lane * 8) =
                cvt8(a, bb);
          }
        } else {
          _Float16* dst = vf + ((size_t)(n * 64 + kt) * 32) * 512;
#pragma unroll
          for (int i = 0; i < 2; i++) {   // emit transposed frag chunks
            int fl = i * 512 + tid;
            int etl = fl >> 6, ln = fl & 63;
            int m15 = ln & 15, q4 = ln >> 4;
            int e_local = etl * 16 + m15;
            half8 h;
#pragma unroll
            for (int j = 0; j < 8; j++) h[j] = (_Float16)lds[q4 * 8 + j][e_local];
            *reinterpret_cast<half8*>(dst + ((size_t)eh * 1024 + fl) * 8) = h;
          }
        }
      }
    }
  }

  cg::this_grid().sync();                 // all frags visible device-wide

  // ------------------------- phase B: R9 attention ------------------------
  float    (*s_part)[32][36] = reinterpret_cast<float (*)[32][36]>(smem);     // 18432 B
  _Float16 (*p_lds)[40]      = reinterpret_cast<_Float16 (*)[40]>(smem + 18432); // 2560 B
  float*    m_lds            = reinterpret_cast<float*>(smem + 18432 + 2560);
  float*    l_lds            = m_lds + 32;
  float*    a_lds            = m_lds + 64;

  const int lane = tid & 63, w = tid >> 6;
  const int m15  = lane & 15, q4 = lane >> 4;
  const int n    = blockIdx.x & 7, qt = blockIdx.x >> 3;   // qt 0..63
  const int ks   = w & 1, es = w >> 1;

  if (tid < 32) { m_lds[tid] = -3.0e38f; l_lds[tid] = 0.0f; }

  // ---- Q fragments resident: 2 strips x 4 est (this wave's e-quarter). 32 VGPR.
  half8 qfr[2][4];
  {
    const uint32_t qbase = ((uint32_t)(n * 128 + qt * 2) * 16 + es * 4) * 512 + (uint32_t)lane * 8;
#pragma unroll
    for (int s = 0; s < 2; s++)
#pragma unroll
      for (int i = 0; i < 4; i++)
        qfr[s][i] = *reinterpret_cast<const half8*>(qf + qbase + (uint32_t)(s * 16 + i) * 512);
  }

  floatx4 oacc[2][4];                       // [strip][et_local], 32 regs (acc)
#pragma unroll
  for (int s = 0; s < 2; s++)
#pragma unroll
    for (int j = 0; j < 4; j++) oacc[s][j] = (floatx4){0.f, 0.f, 0.f, 0.f};

  uint32_t koff = ((uint32_t)(n * 128 + ks) * 16 + es * 4) * 512 + (uint32_t)lane * 8;
  uint32_t voff = ((uint32_t)(n * 64) * 32 + w * 4) * 512 + (uint32_t)lane * 8;

  block_sync_lds();                         // covers m/l init

  for (int t = 0; t < 64; t++) {
    // ---- S phase: K frags transient, direct global->reg (1KB coalesced each)
    half8 kfr[4];
#pragma unroll
    for (int i = 0; i < 4; i++)
      kfr[i] = *reinterpret_cast<const half8*>(kf + koff + (uint32_t)i * 512);
    koff += 16384;                          // 2 rt * 16 est * 512

    floatx4 sacc[2];
    sacc[0] = (floatx4){0.f, 0.f, 0.f, 0.f};
    sacc[1] = (floatx4){0.f, 0.f, 0.f, 0.f};
    __builtin_amdgcn_s_setprio(1);
#pragma unroll
    for (int i = 0; i < 4; i++) {
      sacc[0] = __builtin_amdgcn_mfma_f32_16x16x32_f16(qfr[0][i], kfr[i], sacc[0], 0, 0, 0);
      sacc[1] = __builtin_amdgcn_mfma_f32_16x16x32_f16(qfr[1][i], kfr[i], sacc[1], 0, 0, 0);
    }
    __builtin_amdgcn_s_setprio(0);

    // ---- V prefetch (this tile): issue NOW so the L2 latency hides under
    // b1 + softmax + b2 (kfr dies above, vfr born here: no peak-VGPR change).
    half8 vfr[4];
#pragma unroll
    for (int j = 0; j < 4; j++)
      vfr[j] = *reinterpret_cast<const half8*>(vf + voff + (uint32_t)j * 512);
    voff += 16384;                          // 32 et * 512

    // write partials (C-layout: row = q4*4+r, col = m15)
#pragma unroll
    for (int s = 0; s < 2; s++)
#pragma unroll
      for (int r = 0; r < 4; r++)
        s_part[es][s * 16 + q4 * 4 + r][ks * 16 + m15] = sacc[s][r];
    block_sync_lds();                       // b1

    // ---- softmax: 32 rows x 16 threads, 2 cols each
    {
      const int r = tid >> 4, sub = tid & 15, c = sub * 2;
      float svx = s_part[0][r][c],     svy = s_part[0][r][c + 1];
#pragma unroll
      for (int pl = 1; pl < 4; pl++) { svx += s_part[pl][r][c]; svy += s_part[pl][r][c + 1]; }
      float mx = fmaxf(svx, svy);
#pragma unroll
      for (int o = 1; o < 16; o <<= 1) mx = fmaxf(mx, __shfl_xor(mx, o));
      const float mo = m_lds[r];
      const float mn = fmaxf(mo, mx);
      const float px = __expf(svx - mn), py = __expf(svy - mn);
      float rs = px + py;
#pragma unroll
      for (int o = 1; o < 16; o <<= 1) rs += __shfl_xor(rs, o);
      if (sub == 0) {
        const float al = __expf(mo - mn);
        a_lds[r] = al; m_lds[r] = mn; l_lds[r] = l_lds[r] * al + rs;
      }
      half2 ph; ph[0] = (_Float16)px; ph[1] = (_Float16)py;
      *reinterpret_cast<half2*>(&p_lds[r][c]) = ph;
    }
    block_sync_lds();                       // b2

    // ---- PV phase: P A-frags from LDS, rescale, MFMA (vfr already in flight)
    half8 pfr[2];
    pfr[0] = *reinterpret_cast<const half8*>(&p_lds[m15][q4 * 8]);
    pfr[1] = *reinterpret_cast<const half8*>(&p_lds[16 + m15][q4 * 8]);
    {
      floatx4 al0 = *reinterpret_cast<floatx4*>(&a_lds[q4 * 4]);
      floatx4 al1 = *reinterpret_cast<floatx4*>(&a_lds[16 + q4 * 4]);
#pragma unroll
      for (int j = 0; j < 4; j++) { oacc[0][j] *= al0; oacc[1][j] *= al1; }
    }
    __builtin_amdgcn_s_setprio(1);
#pragma unroll
    for (int j = 0; j < 4; j++) {
      oacc[0][j] = __builtin_amdgcn_mfma_f32_16x16x32_f16(pfr[0], vfr[j], oacc[0][j], 0, 0, 0);
      oacc[1][j] = __builtin_amdgcn_mfma_f32_16x16x32_f16(pfr[1], vfr[j], oacc[1][j], 0, 0, 0);
    }
    __builtin_amdgcn_s_setprio(0);
  }

  // ---- epilogue: divide by l, store fp32 (l_lds final after last b2)
  const int q0 = qt * 32;
#pragma unroll
  for (int s = 0; s < 2; s++) {
    floatx4 lv = *reinterpret_cast<floatx4*>(&l_lds[s * 16 + q4 * 4]);
#pragma unroll
    for (int j = 0; j < 4; j++) {
      const int col = (w * 4 + j) * 16 + m15;
#pragma unroll
      for (int r = 0; r < 4; r++) {
        const int row = s * 16 + q4 * 4 + r;
        out[((size_t)n * SEQ + q0 + row) * EDIM + col] = oacc[s][j][r] / lv[r];
      }
    }
  }
}

// ===========================================================================
// Fallback path A (cooperative launch rejected): two-kernel R9 structure.
// ===========================================================================
__global__ void make_frags(const float* __restrict__ q, const float* __restrict__ k,
                           const float* __restrict__ v,
                           _Float16* __restrict__ qf, _Float16* __restrict__ kf,
                           _Float16* __restrict__ vf) {
  __shared__ float lds[32][260];
  const int tid = threadIdx.x;
  const int seg = blockIdx.x >> 9;        // 0=Q, 1=K, 2=V
  const int b   = blockIdx.x & 511;       // 8 n x 64 kt
  const int n = b >> 6, kt = b & 63;
  const float* src = (seg == 0 ? q : seg == 1 ? k : v) + ((size_t)n * SEQ + kt * 32) * EDIM;

  if (seg < 2) {
    _Float16* dst = (seg == 0 ? qf : kf) + ((size_t)(n * 128 + kt * 2) * 16) * 512;
#pragma unroll
    for (int eh = 0; eh < 2; eh++) {
      if (eh) __syncthreads();
#pragma unroll
      for (int i = 0; i < 8; i++) {
        int c = i * 256 + tid;
        int row = c >> 6, col4 = c & 63;
        float4 x = *reinterpret_cast<const float4*>(src + (size_t)row * EDIM + eh * 256 + col4 * 4);
        *reinterpret_cast<float4*>(&lds[row][col4 * 4]) = x;
      }
      __syncthreads();
#pragma unroll
      for (int i = 0; i < 4; i++) {
        int fl = i * 256 + tid;
        int lane = fl & 63, idx = fl >> 6;
        int est_l = idx & 7, rt_l = idx >> 3;
        int m15 = lane & 15, q4 = lane >> 4;
        const float* p = &lds[rt_l * 16 + m15][est_l * 32 + q4 * 8];
        float4 a = *reinterpret_cast<const float4*>(p);
        float4 bb = *reinterpret_cast<const float4*>(p + 4);
        *reinterpret_cast<half8*>(dst + ((size_t)(rt_l * 16 + eh * 8 + est_l)) * 512 + lane * 8) =
            cvt8(a, bb);
      }
    }
  } else {
    _Float16* dst = vf + ((size_t)(n * 64 + kt) * 32) * 512;
#pragma unroll
    for (int eh = 0; eh < 2; eh++) {
      if (eh) __syncthreads();
#pragma unroll
      for (int i = 0; i < 8; i++) {
        int c = i * 256 + tid;
        int row = c >> 6, col4 = c & 63;
        float4 x = *reinterpret_cast<const float4*>(src + (size_t)row * EDIM + eh * 256 + col4 * 4);
        *reinterpret_cast<float4*>(&lds[row][col4 * 4]) = x;
      }
      __syncthreads();
#pragma unroll
      for (int i = 0; i < 4; i++) {
        int fl = i * 256 + tid;
        int etl = fl >> 6, ln = fl & 63;
        int m15 = ln & 15, q4 = ln >> 4;
        int e_local = etl * 16 + m15;
        half8 h;
#pragma unroll
        for (int j = 0; j < 8; j++) h[j] = (_Float16)lds[q4 * 8 + j][e_local];
        *reinterpret_cast<half8*>(dst + ((size_t)eh * 1024 + fl) * 8) = h;
      }
    }
  }
}

__launch_bounds__(512, 4)
__global__ void attn_fused(const _Float16* __restrict__ qf, const _Float16* __restrict__ kf,
                           const _Float16* __restrict__ vf, float* __restrict__ out) {
  __shared__ float    s_part[4][32][36];
  __shared__ _Float16 p_lds[32][40];
  __shared__ float    m_lds[32], l_lds[32], a_lds[32];

  const int tid  = threadIdx.x;
  const int lane = tid & 63, w = tid >> 6;
  const int m15  = lane & 15, q4 = lane >> 4;
  const int n    = blockIdx.x & 7, qt = blockIdx.x >> 3;
  const int ks   = w & 1, es = w >> 1;

  if (tid < 32) { m_lds[tid] = -3.0e38f; l_lds[tid] = 0.0f; }

  half8 qfr[2][4];
  {
    const uint32_t qbase = ((uint32_t)(n * 128 + qt * 2) * 16 + es * 4) * 512 + (uint32_t)lane * 8;
#pragma unroll
    for (int s = 0; s < 2; s++)
#pragma unroll
      for (int i = 0; i < 4; i++)
        qfr[s][i] = *reinterpret_cast<const half8*>(qf + qbase + (uint32_t)(s * 16 + i) * 512);
  }

  floatx4 oacc[2][4];
#pragma unroll
  for (int s = 0; s < 2; s++)
#pragma unroll
    for (int j = 0; j < 4; j++) oacc[s][j] = (floatx4){0.f, 0.f, 0.f, 0.f};

  uint32_t koff = ((uint32_t)(n * 128 + ks) * 16 + es * 4) * 512 + (uint32_t)lane * 8;
  uint32_t voff = ((uint32_t)(n * 64) * 32 + w * 4) * 512 + (uint32_t)lane * 8;

  block_sync_lds();

  for (int t = 0; t < 64; t++) {
    half8 kfr[4];
#pragma unroll
    for (int i = 0; i < 4; i++)
      kfr[i] = *reinterpret_cast<const half8*>(kf + koff + (uint32_t)i * 512);
    koff += 16384;

    floatx4 sacc[2];
    sacc[0] = (floatx4){0.f, 0.f, 0.f, 0.f};
    sacc[1] = (floatx4){0.f, 0.f, 0.f, 0.f};
    __builtin_amdgcn_s_setprio(1);
#pragma unroll
    for (int i = 0; i < 4; i++) {
      sacc[0] = __builtin_amdgcn_mfma_f32_16x16x32_f16(qfr[0][i], kfr[i], sacc[0], 0, 0, 0);
      sacc[1] = __builtin_amdgcn_mfma_f32_16x16x32_f16(qfr[1][i], kfr[i], sacc[1], 0, 0, 0);
    }
    __builtin_amdgcn_s_setprio(0);

    half8 vfr[4];
#pragma unroll
    for (int j = 0; j < 4; j++)
      vfr[j] = *reinterpret_cast<const half8*>(vf + voff + (uint32_t)j * 512);
    voff += 16384;

#pragma unroll
    for (int s = 0; s < 2; s++)
#pragma unroll
      for (int r = 0; r < 4; r++)
        s_part[es][s * 16 + q4 * 4 + r][ks * 16 + m15] = sacc[s][r];
    block_sync_lds();

    {
      const int r = tid >> 4, sub = tid & 15, c = sub * 2;
      float svx = s_part[0][r][c],     svy = s_part[0][r][c + 1];
#pragma unroll
      for (int pl = 1; pl < 4; pl++) { svx += s_part[pl][r][c]; svy += s_part[pl][r][c + 1]; }
      float mx = fmaxf(svx, svy);
#pragma unroll
      for (int o = 1; o < 16; o <<= 1) mx = fmaxf(mx, __shfl_xor(mx, o));
      const float mo = m_lds[r];
      const float mn = fmaxf(mo, mx);
      const float px = __expf(svx - mn), py = __expf(svy - mn);
      float rs = px + py;
#pragma unroll
      for (int o = 1; o < 16; o <<= 1) rs += __shfl_xor(rs, o);
      if (sub == 0) {
        const float al = __expf(mo - mn);
        a_lds[r] = al; m_lds[r] = mn; l_lds[r] = l_lds[r] * al + rs;
      }
      half2 ph; ph[0] = (_Float16)px; ph[1] = (_Float16)py;
      *reinterpret_cast<half2*>(&p_lds[r][c]) = ph;
    }
    block_sync_lds();

    half8 pfr[2];
    pfr[0] = *reinterpret_cast<const half8*>(&p_lds[m15][q4 * 8]);
    pfr[1] = *reinterpret_cast<const half8*>(&p_lds[16 + m15][q4 * 8]);
    {
      floatx4 al0 = *reinterpret_cast<floatx4*>(&a_lds[q4 * 4]);
      floatx4 al1 = *reinterpret_cast<floatx4*>(&a_lds[16 + q4 * 4]);
#pragma unroll
      for (int j = 0; j < 4; j++) { oacc[0][j] *= al0; oacc[1][j] *= al1; }
    }
    __builtin_amdgcn_s_setprio(1);
#pragma unroll
    for (int j = 0; j < 4; j++) {
      oacc[0][j] = __builtin_amdgcn_mfma_f32_16x16x32_f16(pfr[0], vfr[j], oacc[0][j], 0, 0, 0);
      oacc[1][j] = __builtin_amdgcn_mfma_f32_16x16x32_f16(pfr[1], vfr[j], oacc[1][j], 0, 0, 0);
    }
    __builtin_amdgcn_s_setprio(0);
  }

  const int q0 = qt * 32;
#pragma unroll
  for (int s = 0; s < 2; s++) {
    floatx4 lv = *reinterpret_cast<floatx4*>(&l_lds[s * 16 + q4 * 4]);
#pragma unroll
    for (int j = 0; j < 4; j++) {
      const int col = (w * 4 + j) * 16 + m15;
#pragma unroll
      for (int r = 0; r < 4; r++) {
        const int row = s * 16 + q4 * 4 + r;
        out[((size_t)n * SEQ + q0 + row) * EDIM + col] = oacc[s][j][r] / lv[r];
      }
    }
  }
}

// ---------------------------------------------------------------------------
// Fallback path B (ws too small): fp32 VALU attention, one block per query row.
// ---------------------------------------------------------------------------
__global__ void attn_fallback(const float* __restrict__ q, const float* __restrict__ k,
                              const float* __restrict__ v, float* __restrict__ out) {
  __shared__ float qrow[EDIM];
  __shared__ float sc[SEQ];
  __shared__ float red[16];
  const int tid = threadIdx.x;                    // 256
  const int n = blockIdx.x >> 11, qi = blockIdx.x & 2047;
  const int wv = tid >> 6, ln = tid & 63;
  const float* qp = q + ((size_t)n * SEQ + qi) * EDIM;
  for (int e = tid; e < EDIM; e += 256) qrow[e] = qp[e];
  __syncthreads();
  for (int kk = wv; kk < SEQ; kk += 4) {
    const float* kp = k + ((size_t)n * SEQ + kk) * EDIM;
    float s = 0.f;
    for (int e = ln; e < EDIM; e += 64) s = fmaf(qrow[e], kp[e], s);
    for (int o = 32; o > 0; o >>= 1) s += __shfl_down(s, o);
    if (ln == 0) sc[kk] = s;
  }
  __syncthreads();
  float mx = -3.0e38f;
  for (int kk = tid; kk < SEQ; kk += 256) mx = fmaxf(mx, sc[kk]);
  for (int o = 32; o > 0; o >>= 1) mx = fmaxf(mx, __shfl_down(mx, o));
  if (ln == 0) red[wv] = mx;
  __syncthreads();
  if (tid == 0) {
    float m2 = red[0];
    for (int i = 1; i < 4; i++) m2 = fmaxf(m2, red[i]);
    red[8] = m2;
  }
  __syncthreads();
  const float m = red[8];
  float ls = 0.f;
  for (int kk = tid; kk < SEQ; kk += 256) { float p = __expf(sc[kk] - m); sc[kk] = p; ls += p; }
  for (int o = 32; o > 0; o >>= 1) ls += __shfl_down(ls, o);
  if (ln == 0) red[wv] = ls;
  __syncthreads();
  if (tid == 0) { red[9] = red[0] + red[1] + red[2] + red[3]; }
  __syncthreads();
  const float linv = 1.f / red[9];
  for (int e = tid; e < EDIM; e += 256) {
    float acc = 0.f;
    const float* vp = v + ((size_t)n * SEQ) * EDIM + e;
    for (int kk = 0; kk < SEQ; kk++) acc = fmaf(sc[kk], vp[(size_t)kk * EDIM], acc);
    out[((size_t)n * SEQ + qi) * EDIM + e] = acc * linv;
  }
}

extern "C" void kernel_launch(void* const* d_in, const int* in_sizes, int n_in,
                              void* d_out, int out_size, void* d_ws, size_t ws_size,
                              hipStream_t stream) {
  const float* q = (const float*)d_in[0];
  const float* k = (const float*)d_in[1];
  const float* v = (const float*)d_in[2];
  float* out = (float*)d_out;
  const size_t need = 3 * NE * sizeof(_Float16);   // 50.3 MB
  if (ws_size >= need) {
    _Float16* qf = (_Float16*)d_ws;
    _Float16* kf = qf + NE;
    _Float16* vf = kf + NE;
    void* args[] = {(void*)&q, (void*)&k, (void*)&v,
                    (void*)&qf, (void*)&kf, (void*)&vf, (void*)&out};
    hipError_t err = hipLaunchCooperativeKernel(
        reinterpret_cast<void*>(attn_all), dim3(512), dim3(512), args, 0, stream);
    if (err != hipSuccess) {
      // cooperative enqueue rejected (e.g. capture restrictions): R9 path.
      make_frags<<<1536, 256, 0, stream>>>(q, k, v, qf, kf, vf);
      attn_fused<<<512, 512, 0, stream>>>(qf, kf, vf, out);
    }
  } else {
    attn_fallback<<<16384, 256, 0, stream>>>(q, k, v, out);
  }
}

// Round 6
// 248.384 us; speedup vs baseline: 1.2904x; 1.2904x over previous
//
#include <hip/hip_runtime.h>
#include <stdint.h>

// ---------------------------------------------------------------------------
// Attention: out = softmax(Q K^T) V,  N=8, S=2048, E=512, fp32 in/out.
// R12 = R9 attention with BK=64 (32 tiles instead of 64): halves the number
// of barrier-pairs + shfl-reductions per MFMA (R9's MfmaUtil was 25% with the
// per-tile chain Kload->MFMA->b1->softmax->b2->MFMA dominated by the softmax/
// barrier section). Wave (ks 0..1, es 0..3) owns TWO 16-krow strips.
// Q is gathered inline fp32 (R8/R10-verified path, one-time prologue);
// pre-pass converts K+V only (R10's proven make_frags, 1024 blocks).
// R11 post-mortem: cooperative single-launch ADDED ~15us of launch overhead
// (gap 102us vs 87-96 for two regular launches) and phase A ran no faster
// fused -> cooperative path abandoned.
// ---------------------------------------------------------------------------

typedef __attribute__((ext_vector_type(8))) _Float16 half8;   // MFMA A/B frag
typedef __attribute__((ext_vector_type(4))) _Float16 half4;
typedef __attribute__((ext_vector_type(4))) float    floatx4; // MFMA C/D frag

#define NBATCH 8
#define SEQ    2048
#define EDIM   512
static constexpr size_t NE = (size_t)NBATCH * SEQ * EDIM;  // 8388608 elems/tensor

// Barrier WITHOUT vmcnt drain: LDS ordering only; global loads in flight stay
// in flight (their consumers get compiler-inserted vmcnt waits).
__device__ __forceinline__ void block_sync_lds() {
  asm volatile("s_waitcnt lgkmcnt(0)\n\ts_barrier" ::: "memory");
}

__device__ __forceinline__ half8 cvt8(float4 a, float4 b) {
  half8 h;
  h[0] = (_Float16)a.x; h[1] = (_Float16)a.y; h[2] = (_Float16)a.z; h[3] = (_Float16)a.w;
  h[4] = (_Float16)b.x; h[5] = (_Float16)b.y; h[6] = (_Float16)b.z; h[7] = (_Float16)b.w;
  return h;
}

// ---------------------------------------------------------------------------
// Fragment layout contract (A/B-frag 16x16x32): lane l holds
//   [dim16 = l&15][k = (l>>4)*8 + j].
//  K: kf[((n*128 + rt)*16 + est)*512 + lane*8 + j]   (rt = row>>4, est = e>>5)
//  V: vf[((n*64 + kt)*32 + et)*512 + lane*8 + j]     (kt = krow>>5, et = e>>4,
//        dim16 = e-col, k = krow within 32-tile)
// ---------------------------------------------------------------------------

// --- pre-pass: 1024 blocks = 2 segments (K,V) x 8 n x 64 row-tiles. (R10-proven)
__global__ void make_frags(const float* __restrict__ k, const float* __restrict__ v,
                           _Float16* __restrict__ kf, _Float16* __restrict__ vf) {
  __shared__ float lds[32][260];
  const int tid = threadIdx.x;
  const int seg = blockIdx.x >> 9;        // 0=K, 1=V
  const int b   = blockIdx.x & 511;       // 8 n x 64 kt
  const int n = b >> 6, kt = b & 63;
  const float* src = (seg == 0 ? k : v) + ((size_t)n * SEQ + kt * 32) * EDIM;

  if (seg == 0) {
    _Float16* dst = kf + ((size_t)(n * 128 + kt * 2) * 16) * 512;
#pragma unroll
    for (int eh = 0; eh < 2; eh++) {
      if (eh) __syncthreads();
#pragma unroll
      for (int i = 0; i < 8; i++) {       // stage 32 rows x 256 f32 (coalesced)
        int c = i * 256 + tid;
        int row = c >> 6, col4 = c & 63;
        float4 x = *reinterpret_cast<const float4*>(src + (size_t)row * EDIM + eh * 256 + col4 * 4);
        *reinterpret_cast<float4*>(&lds[row][col4 * 4]) = x;
      }
      __syncthreads();
#pragma unroll
      for (int i = 0; i < 4; i++) {       // emit 1024 half8 chunks / half
        int fl = i * 256 + tid;
        int lane = fl & 63, idx = fl >> 6;        // idx 0..15
        int est_l = idx & 7, rt_l = idx >> 3;     // est_l 0..7, rt_l 0..1
        int m15 = lane & 15, q4 = lane >> 4;
        const float* p = &lds[rt_l * 16 + m15][est_l * 32 + q4 * 8];
        float4 a = *reinterpret_cast<const float4*>(p);
        float4 bb = *reinterpret_cast<const float4*>(p + 4);
        *reinterpret_cast<half8*>(dst + ((size_t)(rt_l * 16 + eh * 8 + est_l)) * 512 + lane * 8) =
            cvt8(a, bb);
      }
    }
  } else {
    _Float16* dst = vf + ((size_t)(n * 64 + kt) * 32) * 512;
#pragma unroll
    for (int eh = 0; eh < 2; eh++) {
      if (eh) __syncthreads();
#pragma unroll
      for (int i = 0; i < 8; i++) {       // stage 32 rows x 256 f32
        int c = i * 256 + tid;
        int row = c >> 6, col4 = c & 63;
        float4 x = *reinterpret_cast<const float4*>(src + (size_t)row * EDIM + eh * 256 + col4 * 4);
        *reinterpret_cast<float4*>(&lds[row][col4 * 4]) = x;
      }
      __syncthreads();
#pragma unroll
      for (int i = 0; i < 4; i++) {       // emit transposed frag chunks
        int fl = i * 256 + tid;
        int etl = fl >> 6, ln = fl & 63;
        int m15 = ln & 15, q4 = ln >> 4;
        int e_local = etl * 16 + m15;
        half8 h;
#pragma unroll
        for (int j = 0; j < 8; j++) h[j] = (_Float16)lds[q4 * 8 + j][e_local];
        *reinterpret_cast<half8*>(dst + ((size_t)eh * 1024 + fl) * 8) = h;
      }
    }
  }
}

// ---------------------------------------------------------------------------
// Fused flash attention, BK=64. Grid 512 = (n = blk&7, qt = blk>>3), 512 thr.
// Wave = (ks = w&1, es = w>>1):
//   S: both 16-q strips x TWO 16-krow strips (kb) x 128-e quarter.
//   softmax: 32 rows x 16 thr, 4 cols each; 4-plane combine.
//   PV: wave owns 64-e slice (et = w*4..w*4+3), 2 k-chunks (kc).
// Per tile (32 tiles): Kload(8x1KB) -> 16 S-MFMA -> Vprefetch(8x1KB) ->
//   s_part -> b1 -> softmax -> b2 -> pfr -> rescale -> 16 PV-MFMA.
// LDS: s_part 4*32*69*4 = 35328 + p_lds 32*72*2 = 4608 + 384 = 36320 B.
// __launch_bounds__(512,4): 2 blocks/CU (LDS 2x36.3KB ok).
// ---------------------------------------------------------------------------
__launch_bounds__(512, 4)
__global__ void attn_fused(const float* __restrict__ q, const _Float16* __restrict__ kf,
                           const _Float16* __restrict__ vf, float* __restrict__ out) {
  __shared__ float    s_part[4][32][69];   // 4 e-quarter partials, 64 cols (+5 pad)
  __shared__ _Float16 p_lds[32][72];       // P fp16 (A-layout source), 64 cols
  __shared__ float    m_lds[32], l_lds[32], a_lds[32];

  const int tid  = threadIdx.x;
  const int lane = tid & 63, w = tid >> 6;
  const int m15  = lane & 15, q4 = lane >> 4;
  const int n    = blockIdx.x & 7, qt = blockIdx.x >> 3;   // qt 0..63
  const int ks   = w & 1, es = w >> 1;

  if (tid < 32) { m_lds[tid] = -3.0e38f; l_lds[tid] = 0.0f; }

  // ---- Q fragments: inline fp32 gather + cvt (one-time; R8/R10-verified).
  // row = qt*32 + s*16 + m15, col = es*128 + i*32 + q4*8. 32 VGPR persistent.
  half8 qfr[2][4];
  {
    const float* qb = q + ((size_t)n * SEQ + qt * 32 + m15) * EDIM + es * 128 + q4 * 8;
#pragma unroll
    for (int s = 0; s < 2; s++)
#pragma unroll
      for (int i = 0; i < 4; i++) {
        const float* src = qb + (size_t)s * 16 * EDIM + i * 32;
        float4 a = *reinterpret_cast<const float4*>(src);
        float4 b = *reinterpret_cast<const float4*>(src + 4);
        qfr[s][i] = cvt8(a, b);
      }
  }

  floatx4 oacc[2][4];                       // [strip][et_local]
#pragma unroll
  for (int s = 0; s < 2; s++)
#pragma unroll
    for (int j = 0; j < 4; j++) oacc[s][j] = (floatx4){0.f, 0.f, 0.f, 0.f};

  // K: rt = t*4 + ks*2 + kb, est = es*4 + i
  uint32_t koff = ((uint32_t)(n * 128 + ks * 2) * 16 + es * 4) * 512 + (uint32_t)lane * 8;
  // V: kt = 2t + kc, et = w*4 + j
  uint32_t voff = ((uint32_t)(n * 64) * 32 + w * 4) * 512 + (uint32_t)lane * 8;

  block_sync_lds();                         // covers m/l init

  for (int t = 0; t < 32; t++) {
    // ---- S phase: 8 K frags (2 krow-strips x 4 est), 1KB coalesced each
    half8 kfr[2][4];
#pragma unroll
    for (int kb = 0; kb < 2; kb++)
#pragma unroll
      for (int i = 0; i < 4; i++)
        kfr[kb][i] = *reinterpret_cast<const half8*>(kf + koff + (uint32_t)(kb * 16 + i) * 512);
    koff += 32768;                          // 4 rt * 16 est * 512

    floatx4 sacc[2][2];
#pragma unroll
    for (int s = 0; s < 2; s++)
#pragma unroll
      for (int kb = 0; kb < 2; kb++) sacc[s][kb] = (floatx4){0.f, 0.f, 0.f, 0.f};
    __builtin_amdgcn_s_setprio(1);
#pragma unroll
    for (int i = 0; i < 4; i++)
#pragma unroll
      for (int kb = 0; kb < 2; kb++) {
        sacc[0][kb] = __builtin_amdgcn_mfma_f32_16x16x32_f16(qfr[0][i], kfr[kb][i], sacc[0][kb], 0, 0, 0);
        sacc[1][kb] = __builtin_amdgcn_mfma_f32_16x16x32_f16(qfr[1][i], kfr[kb][i], sacc[1][kb], 0, 0, 0);
      }
    __builtin_amdgcn_s_setprio(0);

    // ---- V prefetch (both k-chunks of this tile): latency hides under
    // b1 + softmax + b2. kfr dies above, vfr born here.
    half8 vfr[2][4];
#pragma unroll
    for (int kc = 0; kc < 2; kc++)
#pragma unroll
      for (int j = 0; j < 4; j++)
        vfr[kc][j] = *reinterpret_cast<const half8*>(vf + voff + (uint32_t)(kc * 32 + j) * 512);
    voff += 32768;                          // 2 kt * 32 et * 512

    // write partials (C-layout: row = q4*4+r, col = (ks*2+kb)*16 + m15)
#pragma unroll
    for (int s = 0; s < 2; s++)
#pragma unroll
      for (int kb = 0; kb < 2; kb++)
#pragma unroll
        for (int r = 0; r < 4; r++)
          s_part[es][s * 16 + q4 * 4 + r][(ks * 2 + kb) * 16 + m15] = sacc[s][kb][r];
    block_sync_lds();                       // b1

    // ---- softmax: 32 rows x 16 threads, 4 cols each; 4-plane combine
    {
      const int r = tid >> 4, sub = tid & 15, c = sub * 4;
      float sv[4];
#pragma unroll
      for (int x = 0; x < 4; x++) {
        float acc = s_part[0][r][c + x];
#pragma unroll
        for (int pl = 1; pl < 4; pl++) acc += s_part[pl][r][c + x];
        sv[x] = acc;
      }
      float mx = fmaxf(fmaxf(sv[0], sv[1]), fmaxf(sv[2], sv[3]));
#pragma unroll
      for (int o = 1; o < 16; o <<= 1) mx = fmaxf(mx, __shfl_xor(mx, o));
      const float mo = m_lds[r];
      const float mn = fmaxf(mo, mx);
      float p0 = __expf(sv[0] - mn), p1 = __expf(sv[1] - mn);
      float p2 = __expf(sv[2] - mn), p3 = __expf(sv[3] - mn);
      float rs = (p0 + p1) + (p2 + p3);
#pragma unroll
      for (int o = 1; o < 16; o <<= 1) rs += __shfl_xor(rs, o);
      if (sub == 0) {
        const float al = __expf(mo - mn);
        a_lds[r] = al; m_lds[r] = mn; l_lds[r] = l_lds[r] * al + rs;
      }
      half4 ph;
      ph[0] = (_Float16)p0; ph[1] = (_Float16)p1; ph[2] = (_Float16)p2; ph[3] = (_Float16)p3;
      *reinterpret_cast<half4*>(&p_lds[r][c]) = ph;
    }
    block_sync_lds();                       // b2

    // ---- PV phase: P A-frags from LDS, rescale, 16 MFMA (vfr in flight)
    half8 pfr[2][2];
#pragma unroll
    for (int s = 0; s < 2; s++)
#pragma unroll
      for (int kc = 0; kc < 2; kc++)
        pfr[s][kc] = *reinterpret_cast<const half8*>(&p_lds[s * 16 + m15][kc * 32 + q4 * 8]);
    {
      floatx4 al0 = *reinterpret_cast<floatx4*>(&a_lds[q4 * 4]);
      floatx4 al1 = *reinterpret_cast<floatx4*>(&a_lds[16 + q4 * 4]);
#pragma unroll
      for (int j = 0; j < 4; j++) { oacc[0][j] *= al0; oacc[1][j] *= al1; }
    }
    __builtin_amdgcn_s_setprio(1);
#pragma unroll
    for (int j = 0; j < 4; j++)
#pragma unroll
      for (int kc = 0; kc < 2; kc++) {
        oacc[0][j] = __builtin_amdgcn_mfma_f32_16x16x32_f16(pfr[0][kc], vfr[kc][j], oacc[0][j], 0, 0, 0);
        oacc[1][j] = __builtin_amdgcn_mfma_f32_16x16x32_f16(pfr[1][kc], vfr[kc][j], oacc[1][j], 0, 0, 0);
      }
    __builtin_amdgcn_s_setprio(0);
  }

  // ---- epilogue: divide by l, store fp32 (l_lds final after last b2)
  const int q0 = qt * 32;
#pragma unroll
  for (int s = 0; s < 2; s++) {
    floatx4 lv = *reinterpret_cast<floatx4*>(&l_lds[s * 16 + q4 * 4]);
#pragma unroll
    for (int j = 0; j < 4; j++) {
      const int col = (w * 4 + j) * 16 + m15;
#pragma unroll
      for (int r = 0; r < 4; r++) {
        const int row = s * 16 + q4 * 4 + r;
        out[((size_t)n * SEQ + q0 + row) * EDIM + col] = oacc[s][j][r] / lv[r];
      }
    }
  }
}

// ---------------------------------------------------------------------------
// Fallback (ws too small): fp32 VALU attention, one block per query row.
// ---------------------------------------------------------------------------
__global__ void attn_fallback(const float* __restrict__ q, const float* __restrict__ k,
                              const float* __restrict__ v, float* __restrict__ out) {
  __shared__ float qrow[EDIM];
  __shared__ float sc[SEQ];
  __shared__ float red[16];
  const int tid = threadIdx.x;                    // 256
  const int n = blockIdx.x >> 11, qi = blockIdx.x & 2047;
  const int wv = tid >> 6, ln = tid & 63;
  const float* qp = q + ((size_t)n * SEQ + qi) * EDIM;
  for (int e = tid; e < EDIM; e += 256) qrow[e] = qp[e];
  __syncthreads();
  for (int kk = wv; kk < SEQ; kk += 4) {
    const float* kp = k + ((size_t)n * SEQ + kk) * EDIM;
    float s = 0.f;
    for (int e = ln; e < EDIM; e += 64) s = fmaf(qrow[e], kp[e], s);
    for (int o = 32; o > 0; o >>= 1) s += __shfl_down(s, o);
    if (ln == 0) sc[kk] = s;
  }
  __syncthreads();
  float mx = -3.0e38f;
  for (int kk = tid; kk < SEQ; kk += 256) mx = fmaxf(mx, sc[kk]);
  for (int o = 32; o > 0; o >>= 1) mx = fmaxf(mx, __shfl_down(mx, o));
  if (ln == 0) red[wv] = mx;
  __syncthreads();
  if (tid == 0) {
    float m2 = red[0];
    for (int i = 1; i < 4; i++) m2 = fmaxf(m2, red[i]);
    red[8] = m2;
  }
  __syncthreads();
  const float m = red[8];
  float ls = 0.f;
  for (int kk = tid; kk < SEQ; kk += 256) { float p = __expf(sc[kk] - m); sc[kk] = p; ls += p; }
  for (int o = 32; o > 0; o >>= 1) ls += __shfl_down(ls, o);
  if (ln == 0) red[wv] = ls;
  __syncthreads();
  if (tid == 0) { red[9] = red[0] + red[1] + red[2] + red[3]; }
  __syncthreads();
  const float linv = 1.f / red[9];
  for (int e = tid; e < EDIM; e += 256) {
    float acc = 0.f;
    const float* vp = v + ((size_t)n * SEQ) * EDIM + e;
    for (int kk = 0; kk < SEQ; kk++) acc = fmaf(sc[kk], vp[(size_t)kk * EDIM], acc);
    out[((size_t)n * SEQ + qi) * EDIM + e] = acc * linv;
  }
}

extern "C" void kernel_launch(void* const* d_in, const int* in_sizes, int n_in,
                              void* d_out, int out_size, void* d_ws, size_t ws_size,
                              hipStream_t stream) {
  const float* q = (const float*)d_in[0];
  const float* k = (const float*)d_in[1];
  const float* v = (const float*)d_in[2];
  float* out = (float*)d_out;
  const size_t need = 2 * NE * sizeof(_Float16);   // 33.6 MB (K + V frags)
  if (ws_size >= need) {
    _Float16* kf = (_Float16*)d_ws;
    _Float16* vf = kf + NE;
    make_frags<<<1024, 256, 0, stream>>>(k, v, kf, vf);
    attn_fused<<<512, 512, 0, stream>>>(q, kf, vf, out);
  } else {
    attn_fallback<<<16384, 256, 0, stream>>>(q, k, v, out);
  }
}